// Round 1
// baseline (196.824 us; speedup 1.0000x reference)
//
#include <hip/hip_runtime.h>

typedef __attribute__((ext_vector_type(4))) float  floatx4;
typedef __attribute__((ext_vector_type(8))) __bf16 bf16x8;
typedef __attribute__((ext_vector_type(4))) __bf16 bf16x4;

#define NB    4096      // triple batch size
#define DIM   128
#define SLEN  10
#define CN0   20000
#define CN1   2000
#define CN2   15000
#define T1PAD 2048      // padded type-1 table size
#define MT    32        // nodes per workgroup in rnn kernel
#define HSTR  136       // LDS bf16 row stride (pad 8 -> 16B-aligned rows, <=2-way banks)

// ---------------- ws layout (bytes) ----------------
// be0 | be1 | be2 | bwih | bwhh | agg0 | agg1 | tbl1
static constexpr size_t OFF_BE0  = 0;
static constexpr size_t SZ_BE0   = (size_t)CN0 * DIM * 2;
static constexpr size_t OFF_BE1  = OFF_BE0 + SZ_BE0;
static constexpr size_t SZ_BE1   = (size_t)CN1 * DIM * 2;
static constexpr size_t OFF_BE2  = OFF_BE1 + SZ_BE1;
static constexpr size_t SZ_BE2   = (size_t)CN2 * DIM * 2;
static constexpr size_t OFF_WIH  = OFF_BE2 + SZ_BE2;
static constexpr size_t SZ_W     = (size_t)2 * 3 * DIM * DIM * 2;
static constexpr size_t OFF_WHH  = OFF_WIH + SZ_W;
static constexpr size_t OFF_AGG0 = OFF_WHH + SZ_W;
static constexpr size_t SZ_AGG0  = (size_t)6 * NB * DIM * 4;
static constexpr size_t OFF_AGG1 = OFF_AGG0 + SZ_AGG0;
static constexpr size_t SZ_AGG1  = (size_t)6 * T1PAD * DIM * 4;
static constexpr size_t OFF_TBL1 = OFF_AGG1 + SZ_AGG1;

__device__ __forceinline__ float fast_tanh(float x) {
    x = fminf(fmaxf(x, -15.f), 15.f);
    float e = __expf(2.0f * x);
    return (e - 1.0f) * __builtin_amdgcn_rcpf(e + 1.0f);
}

// ---------------- prep: fp32 -> bf16 for embeddings + RNN weights ----------------
__global__ __launch_bounds__(256) void prep_kernel(
    const float* __restrict__ e0, const float* __restrict__ e1, const float* __restrict__ e2,
    const float* __restrict__ wih, const float* __restrict__ whh,
    __bf16* __restrict__ b0, __bf16* __restrict__ b1, __bf16* __restrict__ b2,
    __bf16* __restrict__ bwih, __bf16* __restrict__ bwhh)
{
    int i = blockIdx.x * 256 + threadIdx.x;   // in float4 units
    const int n0 = CN0 * DIM / 4, n1 = CN1 * DIM / 4, n2 = CN2 * DIM / 4;
    const int nw = 2 * 3 * DIM * DIM / 4;
    const float* src; __bf16* dst;
    if (i < n0)              { src = e0;  dst = b0;   }
    else if ((i -= n0) < n1) { src = e1;  dst = b1;   }
    else if ((i -= n1) < n2) { src = e2;  dst = b2;   }
    else if ((i -= n2) < nw) { src = wih; dst = bwih; }
    else if ((i -= nw) < nw) { src = whh; dst = bwhh; }
    else return;
    floatx4 v = ((const floatx4*)src)[i];
    bf16x4 o = { (__bf16)v[0], (__bf16)v[1], (__bf16)v[2], (__bf16)v[3] };
    ((bf16x4*)dst)[i] = o;
}

// ---------------- RNN-mean aggregation ----------------
// Grid: x = 128 tiles (type0, c_ids) + 64 tiles (type1 full table), y = l*3+nt.
// Block: 128 threads = 2 waves. Wave w owns output columns n in [64w, 64w+64).
// Transposed-output MFMA: D'[n][node] = sum_k W[n][k] * X[node][k]
//   A-frag = weight rows (register resident), B-frag = X/H rows (8 consecutive k).
// h kept as bf16 hi+lo pair in LDS (double-buffered) for accuracy.
__global__ __launch_bounds__(128, 2) void rnn_kernel(
    const int* __restrict__ c_ids,
    const int* __restrict__ nb00, const int* __restrict__ nb01, const int* __restrict__ nb02,
    const int* __restrict__ nb10, const int* __restrict__ nb11, const int* __restrict__ nb12,
    const __bf16* __restrict__ be0, const __bf16* __restrict__ be1, const __bf16* __restrict__ be2,
    const __bf16* __restrict__ bwih, const __bf16* __restrict__ bwhh,
    const float* __restrict__ bih, const float* __restrict__ bhh,
    float* __restrict__ agg0, float* __restrict__ agg1)
{
    const int lnt = blockIdx.y;          // l*3 + nt
    const int nt  = lnt % 3;
    int tile = blockIdx.x;
    int group, nodeBase;
    float* aggOut;
    const int* neighTab;
    if (tile < NB / MT) {
        group = 0; nodeBase = tile * MT;
        neighTab = (nt == 0) ? nb00 : (nt == 1) ? nb01 : nb02;
        aggOut = agg0 + (size_t)lnt * NB * DIM;
    } else {
        group = 1; tile -= NB / MT; nodeBase = tile * MT;
        neighTab = (nt == 0) ? nb10 : (nt == 1) ? nb11 : nb12;
        aggOut = agg1 + (size_t)lnt * T1PAD * DIM;
    }
    const __bf16* emb = (nt == 0) ? be0 : (nt == 1) ? be1 : be2;

    __shared__ int    sNid[MT][SLEN];
    __shared__ __bf16 sHhi[2][MT][HSTR];
    __shared__ __bf16 sHlo[2][MT][HSTR];

    const int tid = threadIdx.x;
    if (tid < MT) {
        int node = nodeBase + tid;
        int id = (group == 0) ? c_ids[node] : min(node, CN1 - 1);
        const int* row = neighTab + (size_t)id * SLEN;
        #pragma unroll
        for (int s = 0; s < SLEN; s++) sNid[tid][s] = row[s];
    }
    __syncthreads();

    const int wave = tid >> 6;   // 0..1
    const int lane = tid & 63;
    const int quad = lane >> 4;  // 0..3
    const int l16  = lane & 15;

    // Register-resident weight A-fragments: [atile 0..3][kstep 0..3]
    const __bf16* Wih = bwih + (size_t)lnt * DIM * DIM;
    const __bf16* Whh = bwhh + (size_t)lnt * DIM * DIM;
    bf16x8 wa_ih[4][4], wa_hh[4][4];
    #pragma unroll
    for (int a = 0; a < 4; a++) {
        int row = wave * 64 + a * 16 + l16;
        #pragma unroll
        for (int ks = 0; ks < 4; ks++) {
            int off = row * DIM + ks * 32 + quad * 8;
            wa_ih[a][ks] = *(const bf16x8*)(Wih + off);
            wa_hh[a][ks] = *(const bf16x8*)(Whh + off);
        }
    }
    floatx4 bias[4];
    #pragma unroll
    for (int a = 0; a < 4; a++) {
        int n0 = wave * 64 + a * 16 + quad * 4;
        bias[a] = *(const floatx4*)(bih + lnt * DIM + n0)
                + *(const floatx4*)(bhh + lnt * DIM + n0);
    }

    floatx4 hsum[4][2];   // [atile][btile]
    #pragma unroll
    for (int a = 0; a < 4; a++)
        #pragma unroll
        for (int b = 0; b < 2; b++) hsum[a][b] = (floatx4)0.f;

    for (int s = 0; s < SLEN; s++) {
        const int rb = s & 1, wb = rb ^ 1;
        #pragma unroll
        for (int b = 0; b < 2; b++) {
            const int m = b * 16 + l16;          // node within tile
            const int nid = sNid[m][s];
            const __bf16* xrow = emb + (size_t)nid * DIM;
            bf16x8 xB[4], hHi[4], hLo[4];
            #pragma unroll
            for (int ks = 0; ks < 4; ks++)
                xB[ks] = *(const bf16x8*)(xrow + ks * 32 + quad * 8);
            if (s > 0) {
                #pragma unroll
                for (int ks = 0; ks < 4; ks++) {
                    hHi[ks] = *(const bf16x8*)(&sHhi[rb][m][ks * 32 + quad * 8]);
                    hLo[ks] = *(const bf16x8*)(&sHlo[rb][m][ks * 32 + quad * 8]);
                }
            }
            #pragma unroll
            for (int a = 0; a < 4; a++) {
                floatx4 acc = (floatx4)0.f;
                #pragma unroll
                for (int ks = 0; ks < 4; ks++)
                    acc = __builtin_amdgcn_mfma_f32_16x16x32_bf16(wa_ih[a][ks], xB[ks], acc, 0, 0, 0);
                if (s > 0) {
                    #pragma unroll
                    for (int ks = 0; ks < 4; ks++) {
                        acc = __builtin_amdgcn_mfma_f32_16x16x32_bf16(wa_hh[a][ks], hHi[ks], acc, 0, 0, 0);
                        acc = __builtin_amdgcn_mfma_f32_16x16x32_bf16(wa_hh[a][ks], hLo[ks], acc, 0, 0, 0);
                    }
                }
                floatx4 p = acc + bias[a];
                float h0 = fast_tanh(p[0]);
                float h1 = fast_tanh(p[1]);
                float h2 = fast_tanh(p[2]);
                float h3 = fast_tanh(p[3]);
                hsum[a][b] += (floatx4){h0, h1, h2, h3};
                // hi/lo split for accurate recurrence
                __bf16 a0 = (__bf16)h0, a1 = (__bf16)h1, a2 = (__bf16)h2, a3 = (__bf16)h3;
                bf16x4 hi = {a0, a1, a2, a3};
                bf16x4 lo = { (__bf16)(h0 - (float)a0), (__bf16)(h1 - (float)a1),
                              (__bf16)(h2 - (float)a2), (__bf16)(h3 - (float)a3) };
                int n0 = wave * 64 + a * 16 + quad * 4;
                *(bf16x4*)(&sHhi[wb][m][n0]) = hi;
                *(bf16x4*)(&sHlo[wb][m][n0]) = lo;
            }
        }
        __syncthreads();
    }

    // agg = mean of 10 states
    #pragma unroll
    for (int a = 0; a < 4; a++) {
        int n0 = wave * 64 + a * 16 + quad * 4;
        #pragma unroll
        for (int b = 0; b < 2; b++) {
            int node = nodeBase + b * 16 + l16;
            floatx4 v = hsum[a][b] * 0.1f;
            *(floatx4*)(aggOut + (size_t)node * DIM + n0) = v;
        }
    }
}

// ---------------- attention combine (per node, one wave) ----------------
__device__ __forceinline__ float wsum64(float v) {
    #pragma unroll
    for (int off = 32; off > 0; off >>= 1) v += __shfl_xor(v, off, 64);
    return v;
}

__global__ __launch_bounds__(256) void att_kernel(
    const int* __restrict__ c_ids,
    const float* __restrict__ emb0, const float* __restrict__ emb1,
    const float* __restrict__ attW,
    const float* __restrict__ agg0, const float* __restrict__ agg1,
    float* __restrict__ outc, float* __restrict__ tbl1)
{
    const int wave = threadIdx.x >> 6, lane = threadIdx.x & 63;
    int gb = blockIdx.x;
    int group, node, Nn, ntype;
    const float* aggB; const float* emb;
    if (gb < NB / 4) { group = 0; node = gb * 4 + wave; ntype = 0; aggB = agg0; emb = emb0; Nn = NB; }
    else { group = 1; node = (gb - NB / 4) * 4 + wave; ntype = 1; aggB = agg1; emb = emb1; Nn = T1PAD; }
    int id = (group == 0) ? c_ids[node] : min(node, CN1 - 1);
    int d = lane * 2;
    float2 cur = *(const float2*)(emb + (size_t)id * DIM + d);

    #pragma unroll
    for (int l = 0; l < 2; l++) {
        float2 stk[3];
        #pragma unroll
        for (int k = 0; k < 3; k++)
            stk[k] = *(const float2*)(aggB + ((size_t)(l * 3 + k) * Nn + node) * DIM + d);
        const float* aw = attW + (l * 3 + ntype) * 2 * DIM;
        float2 ac = *(const float2*)(aw + d);
        float2 as = *(const float2*)(aw + DIM + d);
        float pc = ac.x * cur.x + ac.y * cur.y;
        float p0 = as.x * cur.x + as.y * cur.y;
        float p1 = as.x * stk[0].x + as.y * stk[0].y;
        float p2 = as.x * stk[1].x + as.y * stk[1].y;
        float p3 = as.x * stk[2].x + as.y * stk[2].y;
        float base = wsum64(pc);
        float s0 = base + wsum64(p0);
        float s1 = base + wsum64(p1);
        float s2 = base + wsum64(p2);
        float s3 = base + wsum64(p3);
        float mx = fmaxf(fmaxf(s0, s1), fmaxf(s2, s3));
        float e0 = __expf(s0 - mx), e1 = __expf(s1 - mx);
        float e2 = __expf(s2 - mx), e3 = __expf(s3 - mx);
        float rs = __builtin_amdgcn_rcpf(e0 + e1 + e2 + e3);
        float w0 = e0 * rs, w1 = e1 * rs, w2 = e2 * rs, w3 = e3 * rs;
        float nx = w0 * cur.x + w1 * stk[0].x + w2 * stk[1].x + w3 * stk[2].x;
        float ny = w0 * cur.y + w1 * stk[0].y + w2 * stk[1].y + w3 * stk[2].y;
        cur.x = nx > 0.f ? nx : 0.01f * nx;
        cur.y = ny > 0.f ? ny : 0.01f * ny;
    }
    float* dst = (group == 0) ? (outc + (size_t)node * DIM + d) : (tbl1 + (size_t)node * DIM + d);
    *(float2*)dst = cur;
}

// ---------------- gather pos/neg outputs from type-1 table ----------------
__global__ __launch_bounds__(256) void gather_kernel(
    const int* __restrict__ pos_ids, const int* __restrict__ neg_ids,
    const float* __restrict__ tbl1, float* __restrict__ outp, float* __restrict__ outn)
{
    int i = blockIdx.x * 256 + threadIdx.x;   // over 2 * NB * 32 float4s
    const int half = NB * 32;
    const int* ids; float* dst; int j = i;
    if (i < half) { ids = pos_ids; dst = outp; }
    else          { ids = neg_ids; dst = outn; j -= half; }
    int b = j >> 5, c = j & 31;
    int id = ids[b];
    ((floatx4*)dst)[j] = ((const floatx4*)tbl1)[(size_t)id * 32 + c];
}

extern "C" void kernel_launch(void* const* d_in, const int* in_sizes, int n_in,
                              void* d_out, int out_size, void* d_ws, size_t ws_size,
                              hipStream_t stream)
{
    const int* c_ids   = (const int*)d_in[0];
    const int* pos_ids = (const int*)d_in[1];
    const int* neg_ids = (const int*)d_in[2];
    const int* nb00 = (const int*)d_in[3];
    const int* nb01 = (const int*)d_in[4];
    const int* nb02 = (const int*)d_in[5];
    const int* nb10 = (const int*)d_in[6];
    const int* nb11 = (const int*)d_in[7];
    const int* nb12 = (const int*)d_in[8];
    const float* emb0 = (const float*)d_in[12];
    const float* emb1 = (const float*)d_in[13];
    const float* emb2 = (const float*)d_in[14];
    const float* rWih = (const float*)d_in[15];
    const float* rWhh = (const float*)d_in[16];
    const float* rbih = (const float*)d_in[17];
    const float* rbhh = (const float*)d_in[18];
    const float* attW = (const float*)d_in[19];

    char* ws = (char*)d_ws;
    __bf16* be0  = (__bf16*)(ws + OFF_BE0);
    __bf16* be1  = (__bf16*)(ws + OFF_BE1);
    __bf16* be2  = (__bf16*)(ws + OFF_BE2);
    __bf16* bwih = (__bf16*)(ws + OFF_WIH);
    __bf16* bwhh = (__bf16*)(ws + OFF_WHH);
    float*  agg0 = (float*)(ws + OFF_AGG0);
    float*  agg1 = (float*)(ws + OFF_AGG1);
    float*  tbl1 = (float*)(ws + OFF_TBL1);

    float* out  = (float*)d_out;
    float* outc = out;
    float* outp = out + (size_t)NB * DIM;
    float* outn = out + (size_t)2 * NB * DIM;

    // 1) bf16 conversion of embeddings + weights
    {
        int total4 = (CN0 + CN1 + CN2) * DIM / 4 + 2 * (2 * 3 * DIM * DIM / 4);
        int blocks = (total4 + 255) / 256;
        prep_kernel<<<blocks, 256, 0, stream>>>(emb0, emb1, emb2, rWih, rWhh,
                                                be0, be1, be2, bwih, bwhh);
    }
    // 2) RNN-mean aggregations: c batch (4096 nodes) + full type-1 table (2048)
    {
        dim3 grid(NB / MT + T1PAD / MT, 6);
        rnn_kernel<<<grid, 128, 0, stream>>>(c_ids, nb00, nb01, nb02, nb10, nb11, nb12,
                                             be0, be1, be2, bwih, bwhh, rbih, rbhh,
                                             agg0, agg1);
    }
    // 3) attention combine
    {
        int blocks = NB / 4 + T1PAD / 4;
        att_kernel<<<blocks, 256, 0, stream>>>(c_ids, emb0, emb1, attW, agg0, agg1,
                                               outc, tbl1);
    }
    // 4) gather pos/neg outputs
    {
        int blocks = 2 * NB * 32 / 256;
        gather_kernel<<<blocks, 256, 0, stream>>>(pos_ids, neg_ids, tbl1, outp, outn);
    }
}

// Round 2
// 191.834 us; speedup vs baseline: 1.0260x; 1.0260x over previous
//
#include <hip/hip_runtime.h>

typedef __attribute__((ext_vector_type(4))) float  floatx4;
typedef __attribute__((ext_vector_type(8))) __bf16 bf16x8;
typedef __attribute__((ext_vector_type(4))) __bf16 bf16x4;

#define NB    4096      // triple batch size
#define DIM   128
#define SLEN  10
#define CN0   20000
#define CN1   2000
#define CN2   15000
#define T1PAD 2048      // padded type-1 table size
#define GMT   16        // nodes per wave (= per block) in rnn kernel
#define HSTR  136       // LDS bf16 row stride (16B-aligned rows, full-BW b128 reads)

// ---------------- ws layout (bytes) ----------------
// be0 | be1 | be2 | bwih | bwhh | agg0 | agg1 | tbl1
static constexpr size_t OFF_BE0  = 0;
static constexpr size_t SZ_BE0   = (size_t)CN0 * DIM * 2;
static constexpr size_t OFF_BE1  = OFF_BE0 + SZ_BE0;
static constexpr size_t SZ_BE1   = (size_t)CN1 * DIM * 2;
static constexpr size_t OFF_BE2  = OFF_BE1 + SZ_BE1;
static constexpr size_t SZ_BE2   = (size_t)CN2 * DIM * 2;
static constexpr size_t OFF_WIH  = OFF_BE2 + SZ_BE2;
static constexpr size_t SZ_W     = (size_t)2 * 3 * DIM * DIM * 2;
static constexpr size_t OFF_WHH  = OFF_WIH + SZ_W;
static constexpr size_t OFF_AGG0 = OFF_WHH + SZ_W;
static constexpr size_t SZ_AGG0  = (size_t)6 * NB * DIM * 4;
static constexpr size_t OFF_AGG1 = OFF_AGG0 + SZ_AGG0;
static constexpr size_t SZ_AGG1  = (size_t)6 * T1PAD * DIM * 4;
static constexpr size_t OFF_TBL1 = OFF_AGG1 + SZ_AGG1;

__device__ __forceinline__ float fast_tanh(float x) {
    x = fminf(fmaxf(x, -20.f), 20.f);          // single v_med3-able clamp for safety
    float e = __expf(2.0f * x);
    return 1.0f - 2.0f * __builtin_amdgcn_rcpf(e + 1.0f);
}

// ---------------- prep: fp32 -> bf16 for embeddings + RNN weights ----------------
__global__ __launch_bounds__(256) void prep_kernel(
    const float* __restrict__ e0, const float* __restrict__ e1, const float* __restrict__ e2,
    const float* __restrict__ wih, const float* __restrict__ whh,
    __bf16* __restrict__ b0, __bf16* __restrict__ b1, __bf16* __restrict__ b2,
    __bf16* __restrict__ bwih, __bf16* __restrict__ bwhh)
{
    int i = blockIdx.x * 256 + threadIdx.x;   // in float4 units
    const int n0 = CN0 * DIM / 4, n1 = CN1 * DIM / 4, n2 = CN2 * DIM / 4;
    const int nw = 2 * 3 * DIM * DIM / 4;
    const float* src; __bf16* dst;
    if (i < n0)              { src = e0;  dst = b0;   }
    else if ((i -= n0) < n1) { src = e1;  dst = b1;   }
    else if ((i -= n1) < n2) { src = e2;  dst = b2;   }
    else if ((i -= n2) < nw) { src = wih; dst = bwih; }
    else if ((i -= nw) < nw) { src = whh; dst = bwhh; }
    else return;
    floatx4 v = ((const floatx4*)src)[i];
    bf16x4 o = { (__bf16)v[0], (__bf16)v[1], (__bf16)v[2], (__bf16)v[3] };
    ((bf16x4*)dst)[i] = o;
}

// ---------------- RNN-mean aggregation ----------------
// One 64-thread block = one wave = 16 nodes x ALL 128 output columns.
// Transposed-output MFMA: D'[n][node] = sum_k W[n][k] * X[node][k]
//   A-frag = weight rows, fully register-resident (Wih + Whh = 256 VGPRs)
//   B-frag = X/H rows (8 consecutive k per lane)
// h recurrence is wave-private: C-layout -> B-frag transform via wave-private
// LDS (no __syncthreads in the step loop). h kept as bf16 hi+lo for accuracy.
// x gathers are prefetched one step ahead (neighbor ids known up front).
__global__ __launch_bounds__(64, 1) void rnn_kernel(
    const int* __restrict__ c_ids,
    const int* __restrict__ nb00, const int* __restrict__ nb01, const int* __restrict__ nb02,
    const int* __restrict__ nb10, const int* __restrict__ nb11, const int* __restrict__ nb12,
    const __bf16* __restrict__ be0, const __bf16* __restrict__ be1, const __bf16* __restrict__ be2,
    const __bf16* __restrict__ bwih, const __bf16* __restrict__ bwhh,
    const float* __restrict__ bih, const float* __restrict__ bhh,
    float* __restrict__ agg0, float* __restrict__ agg1)
{
    const int lnt = blockIdx.y;          // l*3 + nt
    const int nt  = lnt % 3;
    int tile = blockIdx.x;
    int group, nodeBase;
    float* aggOut;
    const int* neighTab;
    if (tile < NB / GMT) {
        group = 0; nodeBase = tile * GMT;
        neighTab = (nt == 0) ? nb00 : (nt == 1) ? nb01 : nb02;
        aggOut = agg0 + (size_t)lnt * NB * DIM;
    } else {
        group = 1; tile -= NB / GMT; nodeBase = tile * GMT;
        neighTab = (nt == 0) ? nb10 : (nt == 1) ? nb11 : nb12;
        aggOut = agg1 + (size_t)lnt * T1PAD * DIM;
    }
    const __bf16* emb = (nt == 0) ? be0 : (nt == 1) ? be1 : be2;

    __shared__ int    sNid[GMT][SLEN];
    __shared__ __bf16 sHhi[GMT][HSTR];
    __shared__ __bf16 sHlo[GMT][HSTR];

    const int lane = threadIdx.x;        // 0..63
    const int quad = lane >> 4;          // 0..3
    const int l16  = lane & 15;

    if (lane < GMT) {
        int node = nodeBase + lane;
        int id = (group == 0) ? c_ids[node] : min(node, CN1 - 1);
        const int* row = neighTab + (size_t)id * SLEN;
        #pragma unroll
        for (int s = 0; s < SLEN; s++) sNid[lane][s] = row[s];
    }
    __syncthreads();   // once, before the loop

    // Register-resident weight A-fragments for all 8 atiles x 4 ksteps.
    const __bf16* Wih = bwih + (size_t)lnt * DIM * DIM;
    const __bf16* Whh = bwhh + (size_t)lnt * DIM * DIM;
    bf16x8 wih[8][4], whh[8][4];
    #pragma unroll
    for (int a = 0; a < 8; a++) {
        int row = a * 16 + l16;
        #pragma unroll
        for (int ks = 0; ks < 4; ks++) {
            int off = row * DIM + ks * 32 + quad * 8;
            wih[a][ks] = *(const bf16x8*)(Wih + off);
            whh[a][ks] = *(const bf16x8*)(Whh + off);
        }
    }
    floatx4 biasv[8];
    #pragma unroll
    for (int a = 0; a < 8; a++) {
        int n0 = a * 16 + quad * 4;
        biasv[a] = *(const floatx4*)(bih + lnt * DIM + n0)
                 + *(const floatx4*)(bhh + lnt * DIM + n0);
    }

    floatx4 hsum[8];
    #pragma unroll
    for (int a = 0; a < 8; a++) hsum[a] = (floatx4)0.f;

    // prefetch x for s=0: lane holds x[node=l16][ks*32+quad*8 ..+7]
    bf16x8 xb[4];
    {
        int nid = sNid[l16][0];
        const __bf16* xr = emb + (size_t)nid * DIM;
        #pragma unroll
        for (int ks = 0; ks < 4; ks++)
            xb[ks] = *(const bf16x8*)(xr + ks * 32 + quad * 8);
    }

    for (int s = 0; s < SLEN; s++) {
        // h B-frags from previous step (wave-private LDS; lgkmcnt only, no barrier)
        bf16x8 hbhi[4], hblo[4];
        if (s > 0) {
            #pragma unroll
            for (int ks = 0; ks < 4; ks++) {
                hbhi[ks] = *(const bf16x8*)(&sHhi[l16][ks * 32 + quad * 8]);
                hblo[ks] = *(const bf16x8*)(&sHlo[l16][ks * 32 + quad * 8]);
            }
        }
        // prefetch x for next step
        bf16x8 xbn[4];
        if (s < SLEN - 1) {
            int nid = sNid[l16][s + 1];
            const __bf16* xr = emb + (size_t)nid * DIM;
            #pragma unroll
            for (int ks = 0; ks < 4; ks++)
                xbn[ks] = *(const bf16x8*)(xr + ks * 32 + quad * 8);
        }
        #pragma unroll
        for (int a = 0; a < 8; a++) {
            floatx4 acc = (floatx4)0.f;
            #pragma unroll
            for (int ks = 0; ks < 4; ks++)
                acc = __builtin_amdgcn_mfma_f32_16x16x32_bf16(wih[a][ks], xb[ks], acc, 0, 0, 0);
            if (s > 0) {
                #pragma unroll
                for (int ks = 0; ks < 4; ks++) {
                    acc = __builtin_amdgcn_mfma_f32_16x16x32_bf16(whh[a][ks], hbhi[ks], acc, 0, 0, 0);
                    acc = __builtin_amdgcn_mfma_f32_16x16x32_bf16(whh[a][ks], hblo[ks], acc, 0, 0, 0);
                }
            }
            floatx4 p = acc + biasv[a];
            float h0 = fast_tanh(p[0]);
            float h1 = fast_tanh(p[1]);
            float h2 = fast_tanh(p[2]);
            float h3 = fast_tanh(p[3]);
            hsum[a] += (floatx4){h0, h1, h2, h3};
            // hi/lo split; write back in C-layout: rows n = a*16 + quad*4 + r, node l16
            __bf16 a0 = (__bf16)h0, a1 = (__bf16)h1, a2 = (__bf16)h2, a3 = (__bf16)h3;
            bf16x4 hi = {a0, a1, a2, a3};
            bf16x4 lo = { (__bf16)(h0 - (float)a0), (__bf16)(h1 - (float)a1),
                          (__bf16)(h2 - (float)a2), (__bf16)(h3 - (float)a3) };
            int n0 = a * 16 + quad * 4;
            *(bf16x4*)(&sHhi[l16][n0]) = hi;
            *(bf16x4*)(&sHlo[l16][n0]) = lo;
        }
        #pragma unroll
        for (int ks = 0; ks < 4; ks++) xb[ks] = xbn[ks];
    }

    // agg = mean of 10 states
    int node = nodeBase + l16;
    #pragma unroll
    for (int a = 0; a < 8; a++) {
        int n0 = a * 16 + quad * 4;
        *(floatx4*)(aggOut + (size_t)node * DIM + n0) = hsum[a] * 0.1f;
    }
}

// ---------------- attention combine (per node, one wave) ----------------
__device__ __forceinline__ float wsum64(float v) {
    #pragma unroll
    for (int off = 32; off > 0; off >>= 1) v += __shfl_xor(v, off, 64);
    return v;
}

__global__ __launch_bounds__(256) void att_kernel(
    const int* __restrict__ c_ids,
    const float* __restrict__ emb0, const float* __restrict__ emb1,
    const float* __restrict__ attW,
    const float* __restrict__ agg0, const float* __restrict__ agg1,
    float* __restrict__ outc, float* __restrict__ tbl1)
{
    const int wave = threadIdx.x >> 6, lane = threadIdx.x & 63;
    int gb = blockIdx.x;
    int group, node, Nn, ntype;
    const float* aggB; const float* emb;
    if (gb < NB / 4) { group = 0; node = gb * 4 + wave; ntype = 0; aggB = agg0; emb = emb0; Nn = NB; }
    else { group = 1; node = (gb - NB / 4) * 4 + wave; ntype = 1; aggB = agg1; emb = emb1; Nn = T1PAD; }
    int id = (group == 0) ? c_ids[node] : min(node, CN1 - 1);
    int d = lane * 2;
    float2 cur = *(const float2*)(emb + (size_t)id * DIM + d);

    #pragma unroll
    for (int l = 0; l < 2; l++) {
        float2 stk[3];
        #pragma unroll
        for (int k = 0; k < 3; k++)
            stk[k] = *(const float2*)(aggB + ((size_t)(l * 3 + k) * Nn + node) * DIM + d);
        const float* aw = attW + (l * 3 + ntype) * 2 * DIM;
        float2 ac = *(const float2*)(aw + d);
        float2 as = *(const float2*)(aw + DIM + d);
        float pc = ac.x * cur.x + ac.y * cur.y;
        float p0 = as.x * cur.x + as.y * cur.y;
        float p1 = as.x * stk[0].x + as.y * stk[0].y;
        float p2 = as.x * stk[1].x + as.y * stk[1].y;
        float p3 = as.x * stk[2].x + as.y * stk[2].y;
        float base = wsum64(pc);
        float s0 = base + wsum64(p0);
        float s1 = base + wsum64(p1);
        float s2 = base + wsum64(p2);
        float s3 = base + wsum64(p3);
        float mx = fmaxf(fmaxf(s0, s1), fmaxf(s2, s3));
        float e0 = __expf(s0 - mx), e1 = __expf(s1 - mx);
        float e2 = __expf(s2 - mx), e3 = __expf(s3 - mx);
        float rs = __builtin_amdgcn_rcpf(e0 + e1 + e2 + e3);
        float w0 = e0 * rs, w1 = e1 * rs, w2 = e2 * rs, w3 = e3 * rs;
        float nx = w0 * cur.x + w1 * stk[0].x + w2 * stk[1].x + w3 * stk[2].x;
        float ny = w0 * cur.y + w1 * stk[0].y + w2 * stk[1].y + w3 * stk[2].y;
        cur.x = nx > 0.f ? nx : 0.01f * nx;
        cur.y = ny > 0.f ? ny : 0.01f * ny;
    }
    float* dst = (group == 0) ? (outc + (size_t)node * DIM + d) : (tbl1 + (size_t)node * DIM + d);
    *(float2*)dst = cur;
}

// ---------------- gather pos/neg outputs from type-1 table ----------------
__global__ __launch_bounds__(256) void gather_kernel(
    const int* __restrict__ pos_ids, const int* __restrict__ neg_ids,
    const float* __restrict__ tbl1, float* __restrict__ outp, float* __restrict__ outn)
{
    int i = blockIdx.x * 256 + threadIdx.x;   // over 2 * NB * 32 float4s
    const int half = NB * 32;
    const int* ids; float* dst; int j = i;
    if (i < half) { ids = pos_ids; dst = outp; }
    else          { ids = neg_ids; dst = outn; j -= half; }
    int b = j >> 5, c = j & 31;
    int id = ids[b];
    ((floatx4*)dst)[j] = ((const floatx4*)tbl1)[(size_t)id * 32 + c];
}

extern "C" void kernel_launch(void* const* d_in, const int* in_sizes, int n_in,
                              void* d_out, int out_size, void* d_ws, size_t ws_size,
                              hipStream_t stream)
{
    const int* c_ids   = (const int*)d_in[0];
    const int* pos_ids = (const int*)d_in[1];
    const int* neg_ids = (const int*)d_in[2];
    const int* nb00 = (const int*)d_in[3];
    const int* nb01 = (const int*)d_in[4];
    const int* nb02 = (const int*)d_in[5];
    const int* nb10 = (const int*)d_in[6];
    const int* nb11 = (const int*)d_in[7];
    const int* nb12 = (const int*)d_in[8];
    const float* emb0 = (const float*)d_in[12];
    const float* emb1 = (const float*)d_in[13];
    const float* emb2 = (const float*)d_in[14];
    const float* rWih = (const float*)d_in[15];
    const float* rWhh = (const float*)d_in[16];
    const float* rbih = (const float*)d_in[17];
    const float* rbhh = (const float*)d_in[18];
    const float* attW = (const float*)d_in[19];

    char* ws = (char*)d_ws;
    __bf16* be0  = (__bf16*)(ws + OFF_BE0);
    __bf16* be1  = (__bf16*)(ws + OFF_BE1);
    __bf16* be2  = (__bf16*)(ws + OFF_BE2);
    __bf16* bwih = (__bf16*)(ws + OFF_WIH);
    __bf16* bwhh = (__bf16*)(ws + OFF_WHH);
    float*  agg0 = (float*)(ws + OFF_AGG0);
    float*  agg1 = (float*)(ws + OFF_AGG1);
    float*  tbl1 = (float*)(ws + OFF_TBL1);

    float* out  = (float*)d_out;
    float* outc = out;
    float* outp = out + (size_t)NB * DIM;
    float* outn = out + (size_t)2 * NB * DIM;

    // 1) bf16 conversion of embeddings + weights
    {
        int total4 = (CN0 + CN1 + CN2) * DIM / 4 + 2 * (2 * 3 * DIM * DIM / 4);
        int blocks = (total4 + 255) / 256;
        prep_kernel<<<blocks, 256, 0, stream>>>(emb0, emb1, emb2, rWih, rWhh,
                                                be0, be1, be2, bwih, bwhh);
    }
    // 2) RNN-mean aggregations: c batch (4096 nodes) + full type-1 table (2048)
    {
        dim3 grid(NB / GMT + T1PAD / GMT, 6);
        rnn_kernel<<<grid, 64, 0, stream>>>(c_ids, nb00, nb01, nb02, nb10, nb11, nb12,
                                            be0, be1, be2, bwih, bwhh, rbih, rbhh,
                                            agg0, agg1);
    }
    // 3) attention combine
    {
        int blocks = NB / 4 + T1PAD / 4;
        att_kernel<<<blocks, 256, 0, stream>>>(c_ids, emb0, emb1, attW, agg0, agg1,
                                               outc, tbl1);
    }
    // 4) gather pos/neg outputs
    {
        int blocks = 2 * NB * 32 / 256;
        gather_kernel<<<blocks, 256, 0, stream>>>(pos_ids, neg_ids, tbl1, outp, outn);
    }
}

// Round 3
// 175.531 us; speedup vs baseline: 1.1213x; 1.0929x over previous
//
#include <hip/hip_runtime.h>

typedef __attribute__((ext_vector_type(4))) float     floatx4;
typedef __attribute__((ext_vector_type(8))) _Float16  f16x8;
typedef __attribute__((ext_vector_type(4))) _Float16  f16x4;

#define NB    4096      // triple batch size
#define DIM   128
#define SLEN  10
#define CN0   20000
#define CN1   2000
#define CN2   15000
#define T1PAD 2048      // padded type-1 table size
#define NODES 32        // nodes per block in rnn kernel
#define HSTR  136       // LDS f16 row stride: 16B-aligned rows, 2-way banks only

// ---------------- ws layout (bytes) ----------------
// he0 | he1 | he2 | hwih | hwhh | agg0 | agg1 | tbl1
static constexpr size_t OFF_HE0  = 0;
static constexpr size_t SZ_HE0   = (size_t)CN0 * DIM * 2;
static constexpr size_t OFF_HE1  = OFF_HE0 + SZ_HE0;
static constexpr size_t SZ_HE1   = (size_t)CN1 * DIM * 2;
static constexpr size_t OFF_HE2  = OFF_HE1 + SZ_HE1;
static constexpr size_t SZ_HE2   = (size_t)CN2 * DIM * 2;
static constexpr size_t OFF_WIH  = OFF_HE2 + SZ_HE2;
static constexpr size_t SZ_W     = (size_t)2 * 3 * DIM * DIM * 2;
static constexpr size_t OFF_WHH  = OFF_WIH + SZ_W;
static constexpr size_t OFF_AGG0 = OFF_WHH + SZ_W;
static constexpr size_t SZ_AGG0  = (size_t)6 * NB * DIM * 4;
static constexpr size_t OFF_AGG1 = OFF_AGG0 + SZ_AGG0;
static constexpr size_t SZ_AGG1  = (size_t)6 * T1PAD * DIM * 4;
static constexpr size_t OFF_TBL1 = OFF_AGG1 + SZ_AGG1;

__device__ __forceinline__ float fast_tanh(float x) {
    // 1 - 2/(e^{2x}+1): self-saturating at +/-inf, no clamp needed
    float e = __expf(2.0f * x);
    return 1.0f - 2.0f * __builtin_amdgcn_rcpf(e + 1.0f);
}

// ---------------- prep: fp32 -> fp16 for embeddings + RNN weights ----------------
__global__ __launch_bounds__(256) void prep_kernel(
    const float* __restrict__ e0, const float* __restrict__ e1, const float* __restrict__ e2,
    const float* __restrict__ wih, const float* __restrict__ whh,
    _Float16* __restrict__ h0, _Float16* __restrict__ h1, _Float16* __restrict__ h2,
    _Float16* __restrict__ hwih, _Float16* __restrict__ hwhh)
{
    int i = blockIdx.x * 256 + threadIdx.x;   // in float4 units
    const int n0 = CN0 * DIM / 4, n1 = CN1 * DIM / 4, n2 = CN2 * DIM / 4;
    const int nw = 2 * 3 * DIM * DIM / 4;
    const float* src; _Float16* dst;
    if (i < n0)              { src = e0;  dst = h0;   }
    else if ((i -= n0) < n1) { src = e1;  dst = h1;   }
    else if ((i -= n1) < n2) { src = e2;  dst = h2;   }
    else if ((i -= n2) < nw) { src = wih; dst = hwih; }
    else if ((i -= nw) < nw) { src = whh; dst = hwhh; }
    else return;
    floatx4 v = ((const floatx4*)src)[i];
    f16x4 o = { (_Float16)v[0], (_Float16)v[1], (_Float16)v[2], (_Float16)v[3] };
    ((f16x4*)dst)[i] = o;
}

// ---------------- RNN-mean aggregation ----------------
// Block = 256 threads = 4 waves, 32 nodes. Wave w owns output cols [32w,32w+32).
// Transposed-output MFMA: D'[n][node] = sum_k W[n][k] * X[node][k]
//   A-frag = weight rows (64 VGPRs/wave -> 2+ waves/SIMD), B-frag = X/H rows.
// h is fp16 (no hi/lo split needed at 2^-11 rounding), double-buffered in LDS,
// exchanged across waves with ONE barrier per step. x gathers prefetched 1 step.
__global__ __launch_bounds__(256, 2) void rnn_kernel(
    const int* __restrict__ c_ids,
    const int* __restrict__ nb00, const int* __restrict__ nb01, const int* __restrict__ nb02,
    const int* __restrict__ nb10, const int* __restrict__ nb11, const int* __restrict__ nb12,
    const _Float16* __restrict__ he0, const _Float16* __restrict__ he1, const _Float16* __restrict__ he2,
    const _Float16* __restrict__ hwih, const _Float16* __restrict__ hwhh,
    const float* __restrict__ bih, const float* __restrict__ bhh,
    float* __restrict__ agg0, float* __restrict__ agg1)
{
    const int lnt = blockIdx.y;          // l*3 + nt
    const int nt  = lnt % 3;
    int tile = blockIdx.x;
    int group, nodeBase;
    float* aggOut;
    const int* neighTab;
    if (tile < NB / NODES) {
        group = 0; nodeBase = tile * NODES;
        neighTab = (nt == 0) ? nb00 : (nt == 1) ? nb01 : nb02;
        aggOut = agg0 + (size_t)lnt * NB * DIM;
    } else {
        group = 1; tile -= NB / NODES; nodeBase = tile * NODES;
        neighTab = (nt == 0) ? nb10 : (nt == 1) ? nb11 : nb12;
        aggOut = agg1 + (size_t)lnt * T1PAD * DIM;
    }
    const _Float16* emb = (nt == 0) ? he0 : (nt == 1) ? he1 : he2;

    __shared__ int      sNid[NODES][SLEN];
    __shared__ _Float16 sH[2][NODES][HSTR];

    const int tid  = threadIdx.x;
    const int wave = tid >> 6;           // 0..3: owns cols [32w, 32w+32)
    const int lane = tid & 63;
    const int quad = lane >> 4;          // 0..3
    const int l16  = lane & 15;

    for (int i = tid; i < NODES * SLEN; i += 256) {
        int n = i / SLEN, s = i - n * SLEN;
        int node = nodeBase + n;
        int id = (group == 0) ? c_ids[node] : min(node, CN1 - 1);
        sNid[n][s] = neighTab[(size_t)id * SLEN + s];
    }
    __syncthreads();

    // Register-resident weight A-fragments: [atile 0..1][kstep 0..3]
    const _Float16* Wih = hwih + (size_t)lnt * DIM * DIM;
    const _Float16* Whh = hwhh + (size_t)lnt * DIM * DIM;
    f16x8 wih[2][4], whh[2][4];
    #pragma unroll
    for (int a = 0; a < 2; a++) {
        int row = wave * 32 + a * 16 + l16;
        #pragma unroll
        for (int ks = 0; ks < 4; ks++) {
            int off = row * DIM + ks * 32 + quad * 8;
            wih[a][ks] = *(const f16x8*)(Wih + off);
            whh[a][ks] = *(const f16x8*)(Whh + off);
        }
    }
    floatx4 biasv[2];
    #pragma unroll
    for (int a = 0; a < 2; a++) {
        int n0 = wave * 32 + a * 16 + quad * 4;
        biasv[a] = *(const floatx4*)(bih + lnt * DIM + n0)
                 + *(const floatx4*)(bhh + lnt * DIM + n0);
    }

    floatx4 hsum[2][2];   // [atile][btile]
    #pragma unroll
    for (int a = 0; a < 2; a++)
        #pragma unroll
        for (int b = 0; b < 2; b++) hsum[a][b] = (floatx4)0.f;

    // prefetch x for s=0: lane holds x[node=b*16+l16][ks*32+quad*8 ..+7]
    f16x8 xb[2][4];
    #pragma unroll
    for (int b = 0; b < 2; b++) {
        int nid = sNid[b * 16 + l16][0];
        const _Float16* xr = emb + (size_t)nid * DIM;
        #pragma unroll
        for (int ks = 0; ks < 4; ks++)
            xb[b][ks] = *(const f16x8*)(xr + ks * 32 + quad * 8);
    }

    for (int s = 0; s < SLEN; s++) {
        const int rb = (s + 1) & 1, wb = s & 1;   // h_s -> buf[s&1]
        // h B-frags from previous step (both waves' columns)
        f16x8 hb[2][4];
        if (s > 0) {
            #pragma unroll
            for (int b = 0; b < 2; b++)
                #pragma unroll
                for (int ks = 0; ks < 4; ks++)
                    hb[b][ks] = *(const f16x8*)(&sH[rb][b * 16 + l16][ks * 32 + quad * 8]);
        }
        // prefetch x for next step
        f16x8 xbn[2][4];
        if (s < SLEN - 1) {
            #pragma unroll
            for (int b = 0; b < 2; b++) {
                int nid = sNid[b * 16 + l16][s + 1];
                const _Float16* xr = emb + (size_t)nid * DIM;
                #pragma unroll
                for (int ks = 0; ks < 4; ks++)
                    xbn[b][ks] = *(const f16x8*)(xr + ks * 32 + quad * 8);
            }
        }
        #pragma unroll
        for (int a = 0; a < 2; a++) {
            #pragma unroll
            for (int b = 0; b < 2; b++) {
                floatx4 acc = (floatx4)0.f;
                #pragma unroll
                for (int ks = 0; ks < 4; ks++)
                    acc = __builtin_amdgcn_mfma_f32_16x16x32_f16(wih[a][ks], xb[b][ks], acc, 0, 0, 0);
                if (s > 0) {
                    #pragma unroll
                    for (int ks = 0; ks < 4; ks++)
                        acc = __builtin_amdgcn_mfma_f32_16x16x32_f16(whh[a][ks], hb[b][ks], acc, 0, 0, 0);
                }
                floatx4 p = acc + biasv[a];
                float h0 = fast_tanh(p[0]);
                float h1 = fast_tanh(p[1]);
                float h2 = fast_tanh(p[2]);
                float h3 = fast_tanh(p[3]);
                hsum[a][b] += (floatx4){h0, h1, h2, h3};
                f16x4 hq = { (_Float16)h0, (_Float16)h1, (_Float16)h2, (_Float16)h3 };
                int n0 = wave * 32 + a * 16 + quad * 4;
                *(f16x4*)(&sH[wb][b * 16 + l16][n0]) = hq;   // ds_write_b64
            }
        }
        #pragma unroll
        for (int b = 0; b < 2; b++)
            #pragma unroll
            for (int ks = 0; ks < 4; ks++) xb[b][ks] = xbn[b][ks];
        __syncthreads();   // h_s visible to all waves before step s+1 reads
    }

    // agg = mean of 10 states
    #pragma unroll
    for (int a = 0; a < 2; a++) {
        int n0 = wave * 32 + a * 16 + quad * 4;
        #pragma unroll
        for (int b = 0; b < 2; b++) {
            int node = nodeBase + b * 16 + l16;
            *(floatx4*)(aggOut + (size_t)node * DIM + n0) = hsum[a][b] * 0.1f;
        }
    }
}

// ---------------- attention combine (per node, one wave) ----------------
__device__ __forceinline__ float wsum64(float v) {
    #pragma unroll
    for (int off = 32; off > 0; off >>= 1) v += __shfl_xor(v, off, 64);
    return v;
}

__global__ __launch_bounds__(256) void att_kernel(
    const int* __restrict__ c_ids,
    const float* __restrict__ emb0, const float* __restrict__ emb1,
    const float* __restrict__ attW,
    const float* __restrict__ agg0, const float* __restrict__ agg1,
    float* __restrict__ outc, float* __restrict__ tbl1)
{
    const int wave = threadIdx.x >> 6, lane = threadIdx.x & 63;
    int gb = blockIdx.x;
    int group, node, Nn, ntype;
    const float* aggB; const float* emb;
    if (gb < NB / 4) { group = 0; node = gb * 4 + wave; ntype = 0; aggB = agg0; emb = emb0; Nn = NB; }
    else { group = 1; node = (gb - NB / 4) * 4 + wave; ntype = 1; aggB = agg1; emb = emb1; Nn = T1PAD; }
    int id = (group == 0) ? c_ids[node] : min(node, CN1 - 1);
    int d = lane * 2;
    float2 cur = *(const float2*)(emb + (size_t)id * DIM + d);

    #pragma unroll
    for (int l = 0; l < 2; l++) {
        float2 stk[3];
        #pragma unroll
        for (int k = 0; k < 3; k++)
            stk[k] = *(const float2*)(aggB + ((size_t)(l * 3 + k) * Nn + node) * DIM + d);
        const float* aw = attW + (l * 3 + ntype) * 2 * DIM;
        float2 ac = *(const float2*)(aw + d);
        float2 as = *(const float2*)(aw + DIM + d);
        float pc = ac.x * cur.x + ac.y * cur.y;
        float p0 = as.x * cur.x + as.y * cur.y;
        float p1 = as.x * stk[0].x + as.y * stk[0].y;
        float p2 = as.x * stk[1].x + as.y * stk[1].y;
        float p3 = as.x * stk[2].x + as.y * stk[2].y;
        float base = wsum64(pc);
        float s0 = base + wsum64(p0);
        float s1 = base + wsum64(p1);
        float s2 = base + wsum64(p2);
        float s3 = base + wsum64(p3);
        float mx = fmaxf(fmaxf(s0, s1), fmaxf(s2, s3));
        float e0 = __expf(s0 - mx), e1 = __expf(s1 - mx);
        float e2 = __expf(s2 - mx), e3 = __expf(s3 - mx);
        float rs = __builtin_amdgcn_rcpf(e0 + e1 + e2 + e3);
        float w0 = e0 * rs, w1 = e1 * rs, w2 = e2 * rs, w3 = e3 * rs;
        float nx = w0 * cur.x + w1 * stk[0].x + w2 * stk[1].x + w3 * stk[2].x;
        float ny = w0 * cur.y + w1 * stk[0].y + w2 * stk[1].y + w3 * stk[2].y;
        cur.x = nx > 0.f ? nx : 0.01f * nx;
        cur.y = ny > 0.f ? ny : 0.01f * ny;
    }
    float* dst = (group == 0) ? (outc + (size_t)node * DIM + d) : (tbl1 + (size_t)node * DIM + d);
    *(float2*)dst = cur;
}

// ---------------- gather pos/neg outputs from type-1 table ----------------
__global__ __launch_bounds__(256) void gather_kernel(
    const int* __restrict__ pos_ids, const int* __restrict__ neg_ids,
    const float* __restrict__ tbl1, float* __restrict__ outp, float* __restrict__ outn)
{
    int i = blockIdx.x * 256 + threadIdx.x;   // over 2 * NB * 32 float4s
    const int half = NB * 32;
    const int* ids; float* dst; int j = i;
    if (i < half) { ids = pos_ids; dst = outp; }
    else          { ids = neg_ids; dst = outn; j -= half; }
    int b = j >> 5, c = j & 31;
    int id = ids[b];
    ((floatx4*)dst)[j] = ((const floatx4*)tbl1)[(size_t)id * 32 + c];
}

extern "C" void kernel_launch(void* const* d_in, const int* in_sizes, int n_in,
                              void* d_out, int out_size, void* d_ws, size_t ws_size,
                              hipStream_t stream)
{
    const int* c_ids   = (const int*)d_in[0];
    const int* pos_ids = (const int*)d_in[1];
    const int* neg_ids = (const int*)d_in[2];
    const int* nb00 = (const int*)d_in[3];
    const int* nb01 = (const int*)d_in[4];
    const int* nb02 = (const int*)d_in[5];
    const int* nb10 = (const int*)d_in[6];
    const int* nb11 = (const int*)d_in[7];
    const int* nb12 = (const int*)d_in[8];
    const float* emb0 = (const float*)d_in[12];
    const float* emb1 = (const float*)d_in[13];
    const float* emb2 = (const float*)d_in[14];
    const float* rWih = (const float*)d_in[15];
    const float* rWhh = (const float*)d_in[16];
    const float* rbih = (const float*)d_in[17];
    const float* rbhh = (const float*)d_in[18];
    const float* attW = (const float*)d_in[19];

    char* ws = (char*)d_ws;
    _Float16* he0  = (_Float16*)(ws + OFF_HE0);
    _Float16* he1  = (_Float16*)(ws + OFF_HE1);
    _Float16* he2  = (_Float16*)(ws + OFF_HE2);
    _Float16* hwih = (_Float16*)(ws + OFF_WIH);
    _Float16* hwhh = (_Float16*)(ws + OFF_WHH);
    float*    agg0 = (float*)(ws + OFF_AGG0);
    float*    agg1 = (float*)(ws + OFF_AGG1);
    float*    tbl1 = (float*)(ws + OFF_TBL1);

    float* out  = (float*)d_out;
    float* outc = out;
    float* outp = out + (size_t)NB * DIM;
    float* outn = out + (size_t)2 * NB * DIM;

    // 1) fp16 conversion of embeddings + weights
    {
        int total4 = (CN0 + CN1 + CN2) * DIM / 4 + 2 * (2 * 3 * DIM * DIM / 4);
        int blocks = (total4 + 255) / 256;
        prep_kernel<<<blocks, 256, 0, stream>>>(emb0, emb1, emb2, rWih, rWhh,
                                                he0, he1, he2, hwih, hwhh);
    }
    // 2) RNN-mean aggregations: c batch (4096 nodes) + full type-1 table (2048)
    {
        dim3 grid(NB / NODES + T1PAD / NODES, 6);
        rnn_kernel<<<grid, 256, 0, stream>>>(c_ids, nb00, nb01, nb02, nb10, nb11, nb12,
                                             he0, he1, he2, hwih, hwhh, rbih, rbhh,
                                             agg0, agg1);
    }
    // 3) attention combine
    {
        int blocks = NB / 4 + T1PAD / 4;
        att_kernel<<<blocks, 256, 0, stream>>>(c_ids, emb0, emb1, attW, agg0, agg1,
                                               outc, tbl1);
    }
    // 4) gather pos/neg outputs
    {
        int blocks = 2 * NB * 32 / 256;
        gather_kernel<<<blocks, 256, 0, stream>>>(pos_ids, neg_ids, tbl1, outp, outn);
    }
}

// Round 5
// 171.512 us; speedup vs baseline: 1.1476x; 1.0234x over previous
//
#include <hip/hip_runtime.h>

typedef __attribute__((ext_vector_type(4))) float     floatx4;
typedef __attribute__((ext_vector_type(8))) _Float16  f16x8;
typedef __attribute__((ext_vector_type(4))) _Float16  f16x4;

#define NB    4096      // triple batch size
#define DIM   128
#define SLEN  10
#define CN0   20000
#define CN1   2000
#define CN2   15000
#define T1PAD 2048      // padded type-1 table size
#define GMT   16        // nodes per wave (= per block) in rnn kernel
#define HSTR  136       // LDS f16 row stride: 16B-aligned rows, <=2-way banks on b128 reads

// ---------------- ws layout (bytes) ----------------
// he0 | he1 | he2 | hwih | hwhh | agg0 | agg1 | tbl1
static constexpr size_t OFF_HE0  = 0;
static constexpr size_t SZ_HE0   = (size_t)CN0 * DIM * 2;
static constexpr size_t OFF_HE1  = OFF_HE0 + SZ_HE0;
static constexpr size_t SZ_HE1   = (size_t)CN1 * DIM * 2;
static constexpr size_t OFF_HE2  = OFF_HE1 + SZ_HE1;
static constexpr size_t SZ_HE2   = (size_t)CN2 * DIM * 2;
static constexpr size_t OFF_WIH  = OFF_HE2 + SZ_HE2;
static constexpr size_t SZ_W     = (size_t)2 * 3 * DIM * DIM * 2;
static constexpr size_t OFF_WHH  = OFF_WIH + SZ_W;
static constexpr size_t OFF_AGG0 = OFF_WHH + SZ_W;
static constexpr size_t SZ_AGG0  = (size_t)6 * NB * DIM * 4;
static constexpr size_t OFF_AGG1 = OFF_AGG0 + SZ_AGG0;
static constexpr size_t SZ_AGG1  = (size_t)6 * T1PAD * DIM * 4;
static constexpr size_t OFF_TBL1 = OFF_AGG1 + SZ_AGG1;

__device__ __forceinline__ float fast_tanh(float x) {
    // 1 - 2/(e^{2x}+1): saturates cleanly at +/-inf (rcp(inf)=0, rcp(1)=1)
    float e = __expf(2.0f * x);
    return 1.0f - 2.0f * __builtin_amdgcn_rcpf(e + 1.0f);
}

// ---------------- prep: fp32 -> fp16 for embeddings + RNN weights ----------------
__global__ __launch_bounds__(256) void prep_kernel(
    const float* __restrict__ e0, const float* __restrict__ e1, const float* __restrict__ e2,
    const float* __restrict__ wih, const float* __restrict__ whh,
    _Float16* __restrict__ h0, _Float16* __restrict__ h1, _Float16* __restrict__ h2,
    _Float16* __restrict__ hwih, _Float16* __restrict__ hwhh)
{
    int i = blockIdx.x * 256 + threadIdx.x;   // in float4 units
    const int n0 = CN0 * DIM / 4, n1 = CN1 * DIM / 4, n2 = CN2 * DIM / 4;
    const int nw = 2 * 3 * DIM * DIM / 4;
    const float* src; _Float16* dst;
    if (i < n0)              { src = e0;  dst = h0;   }
    else if ((i -= n0) < n1) { src = e1;  dst = h1;   }
    else if ((i -= n1) < n2) { src = e2;  dst = h2;   }
    else if ((i -= n2) < nw) { src = wih; dst = hwih; }
    else if ((i -= nw) < nw) { src = whh; dst = hwhh; }
    else return;
    floatx4 v = ((const floatx4*)src)[i];
    f16x4 o = { (_Float16)v[0], (_Float16)v[1], (_Float16)v[2], (_Float16)v[3] };
    ((f16x4*)dst)[i] = o;
}

// ---------------- RNN-mean aggregation (wave-private, barrier-free loop) ----------------
// One 64-thread block = one wave = 16 nodes x ALL 128 output columns.
// Transposed-output MFMA: D'[n][node] = sum_k W[n][k] * X[node][k]
//   A-frag = weight rows, fully register-resident (Wih+Whh fp16 = 256 VGPRs)
//   B-frag = X/H rows (8 consecutive k per lane)
// h recurrence is wave-private: C-layout -> B-frag via wave-private LDS, ordered
// by lgkmcnt only — NO s_barrier in the step loop, so the x prefetch for step
// s+1 stays in flight across step s (no vmcnt(0) drain). The LDS round-trip
// latency is covered by the next step's ih MFMAs (depend only on x).
__global__ __launch_bounds__(64, 1) void rnn_kernel(
    const int* __restrict__ c_ids,
    const int* __restrict__ nb00, const int* __restrict__ nb01, const int* __restrict__ nb02,
    const int* __restrict__ nb10, const int* __restrict__ nb11, const int* __restrict__ nb12,
    const _Float16* __restrict__ he0, const _Float16* __restrict__ he1, const _Float16* __restrict__ he2,
    const _Float16* __restrict__ hwih, const _Float16* __restrict__ hwhh,
    const float* __restrict__ bih, const float* __restrict__ bhh,
    float* __restrict__ agg0, float* __restrict__ agg1)
{
    const int lnt = blockIdx.y;          // l*3 + nt
    const int nt  = lnt % 3;
    int tile = blockIdx.x;
    int group, nodeBase;
    float* aggOut;
    const int* neighTab;
    if (tile < NB / GMT) {
        group = 0; nodeBase = tile * GMT;
        neighTab = (nt == 0) ? nb00 : (nt == 1) ? nb01 : nb02;
        aggOut = agg0 + (size_t)lnt * NB * DIM;
    } else {
        group = 1; tile -= NB / GMT; nodeBase = tile * GMT;
        neighTab = (nt == 0) ? nb10 : (nt == 1) ? nb11 : nb12;
        aggOut = agg1 + (size_t)lnt * T1PAD * DIM;
    }
    const _Float16* emb = (nt == 0) ? he0 : (nt == 1) ? he1 : he2;

    __shared__ int      sNid[GMT][SLEN];
    __shared__ _Float16 sH[GMT][HSTR];

    const int lane = threadIdx.x;        // 0..63
    const int quad = lane >> 4;          // 0..3
    const int l16  = lane & 15;

    if (lane < GMT) {
        int node = nodeBase + lane;
        int id = (group == 0) ? c_ids[node] : min(node, CN1 - 1);
        const int* row = neighTab + (size_t)id * SLEN;
        #pragma unroll
        for (int s = 0; s < SLEN; s++) sNid[lane][s] = row[s];
    }
    __syncthreads();   // once; single wave, near-free

    // Register-resident weight A-fragments: [atile 0..7][kstep 0..3]
    const _Float16* Wih = hwih + (size_t)lnt * DIM * DIM;
    const _Float16* Whh = hwhh + (size_t)lnt * DIM * DIM;
    f16x8 wih[8][4], whh[8][4];
    #pragma unroll
    for (int a = 0; a < 8; a++) {
        int row = a * 16 + l16;
        #pragma unroll
        for (int ks = 0; ks < 4; ks++) {
            int off = row * DIM + ks * 32 + quad * 8;
            wih[a][ks] = *(const f16x8*)(Wih + off);
            whh[a][ks] = *(const f16x8*)(Whh + off);
        }
    }
    floatx4 biasv[8];
    #pragma unroll
    for (int a = 0; a < 8; a++) {
        int n0 = a * 16 + quad * 4;
        biasv[a] = *(const floatx4*)(bih + lnt * DIM + n0)
                 + *(const floatx4*)(bhh + lnt * DIM + n0);
    }

    floatx4 hsum[8];
    #pragma unroll
    for (int a = 0; a < 8; a++) hsum[a] = (floatx4)0.f;

    // x B-frags for step 0: lane holds x[node=l16][ks*32+quad*8 ..+7]
    f16x8 xb[4];
    {
        int nid = sNid[l16][0];
        const _Float16* xr = emb + (size_t)nid * DIM;
        #pragma unroll
        for (int ks = 0; ks < 4; ks++)
            xb[ks] = *(const f16x8*)(xr + ks * 32 + quad * 8);
    }

    // ---- step 0 (ih only), peeled ----
    {
        f16x8 xbn[4];
        {
            int nid = sNid[l16][1];
            const _Float16* xr = emb + (size_t)nid * DIM;
            #pragma unroll
            for (int ks = 0; ks < 4; ks++)
                xbn[ks] = *(const f16x8*)(xr + ks * 32 + quad * 8);
        }
        #pragma unroll
        for (int a = 0; a < 8; a++) {
            floatx4 acc = (floatx4)0.f;
            #pragma unroll
            for (int ks = 0; ks < 4; ks++)
                acc = __builtin_amdgcn_mfma_f32_16x16x32_f16(wih[a][ks], xb[ks], acc, 0, 0, 0);
            floatx4 p = acc + biasv[a];
            float h0 = fast_tanh(p[0]);
            float h1 = fast_tanh(p[1]);
            float h2 = fast_tanh(p[2]);
            float h3 = fast_tanh(p[3]);
            hsum[a] += (floatx4){h0, h1, h2, h3};
            f16x4 hq = { (_Float16)h0, (_Float16)h1, (_Float16)h2, (_Float16)h3 };
            *(f16x4*)(&sH[l16][a * 16 + quad * 4]) = hq;   // ds_write_b64, C-layout
        }
        #pragma unroll
        for (int ks = 0; ks < 4; ks++) xb[ks] = xbn[ks];
    }

    // ---- steps 1..9: ih + hh, no barrier ----
    for (int s = 1; s < SLEN; s++) {
        // prefetch x for step s+1 (clamped index: last iter redoes step 9's row
        // harmlessly — avoids any uninitialized register path)
        f16x8 xbn[4];
        {
            int sn = (s + 1 < SLEN) ? (s + 1) : (SLEN - 1);
            int nid = sNid[l16][sn];
            const _Float16* xr = emb + (size_t)nid * DIM;
            #pragma unroll
            for (int ks = 0; ks < 4; ks++)
                xbn[ks] = *(const f16x8*)(xr + ks * 32 + quad * 8);
        }
        // h_{s-1} B-frags (same-wave LDS ordering via lgkmcnt; no barrier)
        f16x8 hb[4];
        #pragma unroll
        for (int ks = 0; ks < 4; ks++)
            hb[ks] = *(const f16x8*)(&sH[l16][ks * 32 + quad * 8]);

        #pragma unroll
        for (int a = 0; a < 8; a++) {
            floatx4 acc = (floatx4)0.f;
            #pragma unroll
            for (int ks = 0; ks < 4; ks++)
                acc = __builtin_amdgcn_mfma_f32_16x16x32_f16(wih[a][ks], xb[ks], acc, 0, 0, 0);
            #pragma unroll
            for (int ks = 0; ks < 4; ks++)
                acc = __builtin_amdgcn_mfma_f32_16x16x32_f16(whh[a][ks], hb[ks], acc, 0, 0, 0);
            floatx4 p = acc + biasv[a];
            float h0 = fast_tanh(p[0]);
            float h1 = fast_tanh(p[1]);
            float h2 = fast_tanh(p[2]);
            float h3 = fast_tanh(p[3]);
            hsum[a] += (floatx4){h0, h1, h2, h3};
            f16x4 hq = { (_Float16)h0, (_Float16)h1, (_Float16)h2, (_Float16)h3 };
            *(f16x4*)(&sH[l16][a * 16 + quad * 4]) = hq;
        }
        #pragma unroll
        for (int ks = 0; ks < 4; ks++) xb[ks] = xbn[ks];
    }

    // agg = mean of 10 states
    int node = nodeBase + l16;
    #pragma unroll
    for (int a = 0; a < 8; a++) {
        int n0 = a * 16 + quad * 4;
        *(floatx4*)(aggOut + (size_t)node * DIM + n0) = hsum[a] * 0.1f;
    }
}

// ---------------- attention combine (per node, one wave) ----------------
__device__ __forceinline__ float wsum64(float v) {
    #pragma unroll
    for (int off = 32; off > 0; off >>= 1) v += __shfl_xor(v, off, 64);
    return v;
}

__global__ __launch_bounds__(256) void att_kernel(
    const int* __restrict__ c_ids,
    const float* __restrict__ emb0, const float* __restrict__ emb1,
    const float* __restrict__ attW,
    const float* __restrict__ agg0, const float* __restrict__ agg1,
    float* __restrict__ outc, float* __restrict__ tbl1)
{
    const int wave = threadIdx.x >> 6, lane = threadIdx.x & 63;
    int gb = blockIdx.x;
    int group, node, Nn, ntype;
    const float* aggB; const float* emb;
    if (gb < NB / 4) { group = 0; node = gb * 4 + wave; ntype = 0; aggB = agg0; emb = emb0; Nn = NB; }
    else { group = 1; node = (gb - NB / 4) * 4 + wave; ntype = 1; aggB = agg1; emb = emb1; Nn = T1PAD; }
    int id = (group == 0) ? c_ids[node] : min(node, CN1 - 1);
    int d = lane * 2;
    float2 cur = *(const float2*)(emb + (size_t)id * DIM + d);

    #pragma unroll
    for (int l = 0; l < 2; l++) {
        float2 stk[3];
        #pragma unroll
        for (int k = 0; k < 3; k++)
            stk[k] = *(const float2*)(aggB + ((size_t)(l * 3 + k) * Nn + node) * DIM + d);
        const float* aw = attW + (l * 3 + ntype) * 2 * DIM;
        float2 ac = *(const float2*)(aw + d);
        float2 as = *(const float2*)(aw + DIM + d);
        float pc = ac.x * cur.x + ac.y * cur.y;
        float p0 = as.x * cur.x + as.y * cur.y;
        float p1 = as.x * stk[0].x + as.y * stk[0].y;
        float p2 = as.x * stk[1].x + as.y * stk[1].y;
        float p3 = as.x * stk[2].x + as.y * stk[2].y;
        float base = wsum64(pc);
        float s0 = base + wsum64(p0);
        float s1 = base + wsum64(p1);
        float s2 = base + wsum64(p2);
        float s3 = base + wsum64(p3);
        float mx = fmaxf(fmaxf(s0, s1), fmaxf(s2, s3));
        float e0 = __expf(s0 - mx), e1 = __expf(s1 - mx);
        float e2 = __expf(s2 - mx), e3 = __expf(s3 - mx);
        float rs = __builtin_amdgcn_rcpf(e0 + e1 + e2 + e3);
        float w0 = e0 * rs, w1 = e1 * rs, w2 = e2 * rs, w3 = e3 * rs;
        float nx = w0 * cur.x + w1 * stk[0].x + w2 * stk[1].x + w3 * stk[2].x;
        float ny = w0 * cur.y + w1 * stk[0].y + w2 * stk[1].y + w3 * stk[2].y;
        cur.x = nx > 0.f ? nx : 0.01f * nx;
        cur.y = ny > 0.f ? ny : 0.01f * ny;
    }
    float* dst = (group == 0) ? (outc + (size_t)node * DIM + d) : (tbl1 + (size_t)node * DIM + d);
    *(float2*)dst = cur;
}

// ---------------- gather pos/neg outputs from type-1 table ----------------
__global__ __launch_bounds__(256) void gather_kernel(
    const int* __restrict__ pos_ids, const int* __restrict__ neg_ids,
    const float* __restrict__ tbl1, float* __restrict__ outp, float* __restrict__ outn)
{
    int i = blockIdx.x * 256 + threadIdx.x;   // over 2 * NB * 32 float4s
    const int half = NB * 32;
    const int* ids; float* dst; int j = i;
    if (i < half) { ids = pos_ids; dst = outp; }
    else          { ids = neg_ids; dst = outn; j -= half; }
    int b = j >> 5, c = j & 31;
    int id = ids[b];
    ((floatx4*)dst)[j] = ((const floatx4*)tbl1)[(size_t)id * 32 + c];
}

extern "C" void kernel_launch(void* const* d_in, const int* in_sizes, int n_in,
                              void* d_out, int out_size, void* d_ws, size_t ws_size,
                              hipStream_t stream)
{
    const int* c_ids   = (const int*)d_in[0];
    const int* pos_ids = (const int*)d_in[1];
    const int* neg_ids = (const int*)d_in[2];
    const int* nb00 = (const int*)d_in[3];
    const int* nb01 = (const int*)d_in[4];
    const int* nb02 = (const int*)d_in[5];
    const int* nb10 = (const int*)d_in[6];
    const int* nb11 = (const int*)d_in[7];
    const int* nb12 = (const int*)d_in[8];
    const float* emb0 = (const float*)d_in[12];
    const float* emb1 = (const float*)d_in[13];
    const float* emb2 = (const float*)d_in[14];
    const float* rWih = (const float*)d_in[15];
    const float* rWhh = (const float*)d_in[16];
    const float* rbih = (const float*)d_in[17];
    const float* rbhh = (const float*)d_in[18];
    const float* attW = (const float*)d_in[19];

    char* ws = (char*)d_ws;
    _Float16* he0  = (_Float16*)(ws + OFF_HE0);
    _Float16* he1  = (_Float16*)(ws + OFF_HE1);
    _Float16* he2  = (_Float16*)(ws + OFF_HE2);
    _Float16* hwih = (_Float16*)(ws + OFF_WIH);
    _Float16* hwhh = (_Float16*)(ws + OFF_WHH);
    float*    agg0 = (float*)(ws + OFF_AGG0);
    float*    agg1 = (float*)(ws + OFF_AGG1);
    float*    tbl1 = (float*)(ws + OFF_TBL1);

    float* out  = (float*)d_out;
    float* outc = out;
    float* outp = out + (size_t)NB * DIM;
    float* outn = out + (size_t)2 * NB * DIM;

    // 1) fp16 conversion of embeddings + weights
    {
        int total4 = (CN0 + CN1 + CN2) * DIM / 4 + 2 * (2 * 3 * DIM * DIM / 4);
        int blocks = (total4 + 255) / 256;
        prep_kernel<<<blocks, 256, 0, stream>>>(emb0, emb1, emb2, rWih, rWhh,
                                                he0, he1, he2, hwih, hwhh);
    }
    // 2) RNN-mean aggregations: c batch (4096 nodes) + full type-1 table (2048)
    {
        dim3 grid(NB / GMT + T1PAD / GMT, 6);
        rnn_kernel<<<grid, 64, 0, stream>>>(c_ids, nb00, nb01, nb02, nb10, nb11, nb12,
                                            he0, he1, he2, hwih, hwhh, rbih, rbhh,
                                            agg0, agg1);
    }
    // 3) attention combine
    {
        int blocks = NB / 4 + T1PAD / 4;
        att_kernel<<<blocks, 256, 0, stream>>>(c_ids, emb0, emb1, attW, agg0, agg1,
                                               outc, tbl1);
    }
    // 4) gather pos/neg outputs
    {
        int blocks = 2 * NB * 32 / 256;
        gather_kernel<<<blocks, 256, 0, stream>>>(pos_ids, neg_ids, tbl1, outp, outn);
    }
}

// Round 6
// 171.197 us; speedup vs baseline: 1.1497x; 1.0018x over previous
//
#include <hip/hip_runtime.h>

typedef __attribute__((ext_vector_type(4))) float     floatx4;
typedef __attribute__((ext_vector_type(8))) _Float16  f16x8;
typedef __attribute__((ext_vector_type(4))) _Float16  f16x4;

#define NB    4096      // triple batch size
#define DIM   128
#define SLEN  10
#define CN0   20000
#define CN1   2000
#define CN2   15000
#define T1PAD 2048      // padded type-1 table size
#define GMT   16        // nodes per wave (= per block) in rnn kernel
#define HSTR  136       // LDS f16 row stride: 16B-aligned rows, <=2-way banks on b128 reads

// ---------------- ws layout (bytes) ----------------
// he0 | he1 | he2 | hwih | hwhh | agg0 | agg1 | tbl1
static constexpr size_t OFF_HE0  = 0;
static constexpr size_t SZ_HE0   = (size_t)CN0 * DIM * 2;
static constexpr size_t OFF_HE1  = OFF_HE0 + SZ_HE0;
static constexpr size_t SZ_HE1   = (size_t)CN1 * DIM * 2;
static constexpr size_t OFF_HE2  = OFF_HE1 + SZ_HE1;
static constexpr size_t SZ_HE2   = (size_t)CN2 * DIM * 2;
static constexpr size_t OFF_WIH  = OFF_HE2 + SZ_HE2;
static constexpr size_t SZ_W     = (size_t)2 * 3 * DIM * DIM * 2;
static constexpr size_t OFF_WHH  = OFF_WIH + SZ_W;
static constexpr size_t OFF_AGG0 = OFF_WHH + SZ_W;
static constexpr size_t SZ_AGG0  = (size_t)6 * NB * DIM * 4;
static constexpr size_t OFF_AGG1 = OFF_AGG0 + SZ_AGG0;
static constexpr size_t SZ_AGG1  = (size_t)6 * T1PAD * DIM * 4;
static constexpr size_t OFF_TBL1 = OFF_AGG1 + SZ_AGG1;

__device__ __forceinline__ float fast_tanh(float x) {
    // 1 - 2/(e^{2x}+1): saturates cleanly at +/-inf (rcp(inf)=0, rcp(1)=1)
    float e = __expf(2.0f * x);
    return 1.0f - 2.0f * __builtin_amdgcn_rcpf(e + 1.0f);
}

// ---------------- prep: fp32 -> fp16 for embeddings + RNN weights ----------------
__global__ __launch_bounds__(256) void prep_kernel(
    const float* __restrict__ e0, const float* __restrict__ e1, const float* __restrict__ e2,
    const float* __restrict__ wih, const float* __restrict__ whh,
    _Float16* __restrict__ h0, _Float16* __restrict__ h1, _Float16* __restrict__ h2,
    _Float16* __restrict__ hwih, _Float16* __restrict__ hwhh)
{
    int i = blockIdx.x * 256 + threadIdx.x;   // in float4 units
    const int n0 = CN0 * DIM / 4, n1 = CN1 * DIM / 4, n2 = CN2 * DIM / 4;
    const int nw = 2 * 3 * DIM * DIM / 4;
    const float* src; _Float16* dst;
    if (i < n0)              { src = e0;  dst = h0;   }
    else if ((i -= n0) < n1) { src = e1;  dst = h1;   }
    else if ((i -= n1) < n2) { src = e2;  dst = h2;   }
    else if ((i -= n2) < nw) { src = wih; dst = hwih; }
    else if ((i -= nw) < nw) { src = whh; dst = hwhh; }
    else return;
    floatx4 v = ((const floatx4*)src)[i];
    f16x4 o = { (_Float16)v[0], (_Float16)v[1], (_Float16)v[2], (_Float16)v[3] };
    ((f16x4*)dst)[i] = o;
}

// ---------------- RNN-mean aggregation (wave-private, breadth-first MFMA) ----------------
// One 64-thread block = one wave = 16 nodes x ALL 128 output columns.
// Transposed-output MFMA: D'[n][node] = sum_k W[n][k] * X[node][k]
//   A-frag = weight rows, fully register-resident; B-frag = X/H rows.
// Step body is restructured breadth-first: acc[8] initialized to bias (bias as
// MFMA C-input), then ks-outer/atile-inner MFMA loops (8 independent MFMAs per
// dependence level, 8 levels) so the matrix pipe runs at issue rate; then one
// batched tanh pass (32 independent values) pipelines through the trans unit.
// No s_barrier in the loop; h round-trips wave-private LDS (lgkmcnt ordering).
__global__ __launch_bounds__(64, 1) void rnn_kernel(
    const int* __restrict__ c_ids,
    const int* __restrict__ nb00, const int* __restrict__ nb01, const int* __restrict__ nb02,
    const int* __restrict__ nb10, const int* __restrict__ nb11, const int* __restrict__ nb12,
    const _Float16* __restrict__ he0, const _Float16* __restrict__ he1, const _Float16* __restrict__ he2,
    const _Float16* __restrict__ hwih, const _Float16* __restrict__ hwhh,
    const float* __restrict__ bih, const float* __restrict__ bhh,
    float* __restrict__ agg0, float* __restrict__ agg1)
{
    const int lnt = blockIdx.y;          // l*3 + nt
    const int nt  = lnt % 3;
    int tile = blockIdx.x;
    int group, nodeBase;
    float* aggOut;
    const int* neighTab;
    if (tile < NB / GMT) {
        group = 0; nodeBase = tile * GMT;
        neighTab = (nt == 0) ? nb00 : (nt == 1) ? nb01 : nb02;
        aggOut = agg0 + (size_t)lnt * NB * DIM;
    } else {
        group = 1; tile -= NB / GMT; nodeBase = tile * GMT;
        neighTab = (nt == 0) ? nb10 : (nt == 1) ? nb11 : nb12;
        aggOut = agg1 + (size_t)lnt * T1PAD * DIM;
    }
    const _Float16* emb = (nt == 0) ? he0 : (nt == 1) ? he1 : he2;

    __shared__ int      sNid[GMT][SLEN];
    __shared__ _Float16 sH[GMT][HSTR];

    const int lane = threadIdx.x;        // 0..63
    const int quad = lane >> 4;          // 0..3
    const int l16  = lane & 15;

    if (lane < GMT) {
        int node = nodeBase + lane;
        int id = (group == 0) ? c_ids[node] : min(node, CN1 - 1);
        const int* row = neighTab + (size_t)id * SLEN;
        #pragma unroll
        for (int s = 0; s < SLEN; s++) sNid[lane][s] = row[s];
    }
    __syncthreads();   // once; single wave, near-free

    // Register-resident weight A-fragments: [atile 0..7][kstep 0..3]
    const _Float16* Wih = hwih + (size_t)lnt * DIM * DIM;
    const _Float16* Whh = hwhh + (size_t)lnt * DIM * DIM;
    f16x8 wih[8][4], whh[8][4];
    #pragma unroll
    for (int a = 0; a < 8; a++) {
        int row = a * 16 + l16;
        #pragma unroll
        for (int ks = 0; ks < 4; ks++) {
            int off = row * DIM + ks * 32 + quad * 8;
            wih[a][ks] = *(const f16x8*)(Wih + off);
            whh[a][ks] = *(const f16x8*)(Whh + off);
        }
    }
    floatx4 biasv[8];
    #pragma unroll
    for (int a = 0; a < 8; a++) {
        int n0 = a * 16 + quad * 4;
        biasv[a] = *(const floatx4*)(bih + lnt * DIM + n0)
                 + *(const floatx4*)(bhh + lnt * DIM + n0);
    }

    floatx4 hsum[8];
    #pragma unroll
    for (int a = 0; a < 8; a++) hsum[a] = (floatx4)0.f;

    // x B-frags for step 0: lane holds x[node=l16][ks*32+quad*8 ..+7]
    f16x8 xb[4];
    {
        int nid = sNid[l16][0];
        const _Float16* xr = emb + (size_t)nid * DIM;
        #pragma unroll
        for (int ks = 0; ks < 4; ks++)
            xb[ks] = *(const f16x8*)(xr + ks * 32 + quad * 8);
    }

    // ---- step 0 (ih only), peeled ----
    {
        f16x8 xbn[4];
        {
            int nid = sNid[l16][1];
            const _Float16* xr = emb + (size_t)nid * DIM;
            #pragma unroll
            for (int ks = 0; ks < 4; ks++)
                xbn[ks] = *(const f16x8*)(xr + ks * 32 + quad * 8);
        }
        floatx4 acc[8];
        #pragma unroll
        for (int a = 0; a < 8; a++) acc[a] = biasv[a];
        #pragma unroll
        for (int ks = 0; ks < 4; ks++)
            #pragma unroll
            for (int a = 0; a < 8; a++)
                acc[a] = __builtin_amdgcn_mfma_f32_16x16x32_f16(wih[a][ks], xb[ks], acc[a], 0, 0, 0);
        #pragma unroll
        for (int a = 0; a < 8; a++) {
            float h0 = fast_tanh(acc[a][0]);
            float h1 = fast_tanh(acc[a][1]);
            float h2 = fast_tanh(acc[a][2]);
            float h3 = fast_tanh(acc[a][3]);
            hsum[a] += (floatx4){h0, h1, h2, h3};
            f16x4 hq = { (_Float16)h0, (_Float16)h1, (_Float16)h2, (_Float16)h3 };
            *(f16x4*)(&sH[l16][a * 16 + quad * 4]) = hq;   // ds_write_b64, C-layout
        }
        #pragma unroll
        for (int ks = 0; ks < 4; ks++) xb[ks] = xbn[ks];
    }

    // ---- steps 1..9: ih + hh, no barrier, breadth-first ----
    for (int s = 1; s < SLEN; s++) {
        // h_{s-1} B-frags (same-wave LDS ordering via lgkmcnt; no barrier)
        f16x8 hb[4];
        #pragma unroll
        for (int ks = 0; ks < 4; ks++)
            hb[ks] = *(const f16x8*)(&sH[l16][ks * 32 + quad * 8]);
        // prefetch x for step s+1 (clamped index avoids uninitialized path)
        f16x8 xbn[4];
        {
            int sn = (s + 1 < SLEN) ? (s + 1) : (SLEN - 1);
            int nid = sNid[l16][sn];
            const _Float16* xr = emb + (size_t)nid * DIM;
            #pragma unroll
            for (int ks = 0; ks < 4; ks++)
                xbn[ks] = *(const f16x8*)(xr + ks * 32 + quad * 8);
        }
        floatx4 acc[8];
        #pragma unroll
        for (int a = 0; a < 8; a++) acc[a] = biasv[a];
        // ih: 4 dependence levels x 8 independent MFMAs
        #pragma unroll
        for (int ks = 0; ks < 4; ks++)
            #pragma unroll
            for (int a = 0; a < 8; a++)
                acc[a] = __builtin_amdgcn_mfma_f32_16x16x32_f16(wih[a][ks], xb[ks], acc[a], 0, 0, 0);
        // hh: 4 more levels x 8 wide
        #pragma unroll
        for (int ks = 0; ks < 4; ks++)
            #pragma unroll
            for (int a = 0; a < 8; a++)
                acc[a] = __builtin_amdgcn_mfma_f32_16x16x32_f16(whh[a][ks], hb[ks], acc[a], 0, 0, 0);
        // batched tanh: 32 independent values pipeline through the trans unit
        #pragma unroll
        for (int a = 0; a < 8; a++) {
            float h0 = fast_tanh(acc[a][0]);
            float h1 = fast_tanh(acc[a][1]);
            float h2 = fast_tanh(acc[a][2]);
            float h3 = fast_tanh(acc[a][3]);
            hsum[a] += (floatx4){h0, h1, h2, h3};
            f16x4 hq = { (_Float16)h0, (_Float16)h1, (_Float16)h2, (_Float16)h3 };
            *(f16x4*)(&sH[l16][a * 16 + quad * 4]) = hq;
        }
        #pragma unroll
        for (int ks = 0; ks < 4; ks++) xb[ks] = xbn[ks];
    }

    // agg = mean of 10 states
    int node = nodeBase + l16;
    #pragma unroll
    for (int a = 0; a < 8; a++) {
        int n0 = a * 16 + quad * 4;
        *(floatx4*)(aggOut + (size_t)node * DIM + n0) = hsum[a] * 0.1f;
    }
}

// ---------------- attention combine (per node, one wave) ----------------
__device__ __forceinline__ float wsum64(float v) {
    #pragma unroll
    for (int off = 32; off > 0; off >>= 1) v += __shfl_xor(v, off, 64);
    return v;
}

__global__ __launch_bounds__(256) void att_kernel(
    const int* __restrict__ c_ids,
    const float* __restrict__ emb0, const float* __restrict__ emb1,
    const float* __restrict__ attW,
    const float* __restrict__ agg0, const float* __restrict__ agg1,
    float* __restrict__ outc, float* __restrict__ tbl1)
{
    const int wave = threadIdx.x >> 6, lane = threadIdx.x & 63;
    int gb = blockIdx.x;
    int group, node, Nn, ntype;
    const float* aggB; const float* emb;
    if (gb < NB / 4) { group = 0; node = gb * 4 + wave; ntype = 0; aggB = agg0; emb = emb0; Nn = NB; }
    else { group = 1; node = (gb - NB / 4) * 4 + wave; ntype = 1; aggB = agg1; emb = emb1; Nn = T1PAD; }
    int id = (group == 0) ? c_ids[node] : min(node, CN1 - 1);
    int d = lane * 2;
    float2 cur = *(const float2*)(emb + (size_t)id * DIM + d);

    #pragma unroll
    for (int l = 0; l < 2; l++) {
        float2 stk[3];
        #pragma unroll
        for (int k = 0; k < 3; k++)
            stk[k] = *(const float2*)(aggB + ((size_t)(l * 3 + k) * Nn + node) * DIM + d);
        const float* aw = attW + (l * 3 + ntype) * 2 * DIM;
        float2 ac = *(const float2*)(aw + d);
        float2 as = *(const float2*)(aw + DIM + d);
        float pc = ac.x * cur.x + ac.y * cur.y;
        float p0 = as.x * cur.x + as.y * cur.y;
        float p1 = as.x * stk[0].x + as.y * stk[0].y;
        float p2 = as.x * stk[1].x + as.y * stk[1].y;
        float p3 = as.x * stk[2].x + as.y * stk[2].y;
        float base = wsum64(pc);
        float s0 = base + wsum64(p0);
        float s1 = base + wsum64(p1);
        float s2 = base + wsum64(p2);
        float s3 = base + wsum64(p3);
        float mx = fmaxf(fmaxf(s0, s1), fmaxf(s2, s3));
        float e0 = __expf(s0 - mx), e1 = __expf(s1 - mx);
        float e2 = __expf(s2 - mx), e3 = __expf(s3 - mx);
        float rs = __builtin_amdgcn_rcpf(e0 + e1 + e2 + e3);
        float w0 = e0 * rs, w1 = e1 * rs, w2 = e2 * rs, w3 = e3 * rs;
        float nx = w0 * cur.x + w1 * stk[0].x + w2 * stk[1].x + w3 * stk[2].x;
        float ny = w0 * cur.y + w1 * stk[0].y + w2 * stk[1].y + w3 * stk[2].y;
        cur.x = nx > 0.f ? nx : 0.01f * nx;
        cur.y = ny > 0.f ? ny : 0.01f * ny;
    }
    float* dst = (group == 0) ? (outc + (size_t)node * DIM + d) : (tbl1 + (size_t)node * DIM + d);
    *(float2*)dst = cur;
}

// ---------------- gather pos/neg outputs from type-1 table ----------------
__global__ __launch_bounds__(256) void gather_kernel(
    const int* __restrict__ pos_ids, const int* __restrict__ neg_ids,
    const float* __restrict__ tbl1, float* __restrict__ outp, float* __restrict__ outn)
{
    int i = blockIdx.x * 256 + threadIdx.x;   // over 2 * NB * 32 float4s
    const int half = NB * 32;
    const int* ids; float* dst; int j = i;
    if (i < half) { ids = pos_ids; dst = outp; }
    else          { ids = neg_ids; dst = outn; j -= half; }
    int b = j >> 5, c = j & 31;
    int id = ids[b];
    ((floatx4*)dst)[j] = ((const floatx4*)tbl1)[(size_t)id * 32 + c];
}

extern "C" void kernel_launch(void* const* d_in, const int* in_sizes, int n_in,
                              void* d_out, int out_size, void* d_ws, size_t ws_size,
                              hipStream_t stream)
{
    const int* c_ids   = (const int*)d_in[0];
    const int* pos_ids = (const int*)d_in[1];
    const int* neg_ids = (const int*)d_in[2];
    const int* nb00 = (const int*)d_in[3];
    const int* nb01 = (const int*)d_in[4];
    const int* nb02 = (const int*)d_in[5];
    const int* nb10 = (const int*)d_in[6];
    const int* nb11 = (const int*)d_in[7];
    const int* nb12 = (const int*)d_in[8];
    const float* emb0 = (const float*)d_in[12];
    const float* emb1 = (const float*)d_in[13];
    const float* emb2 = (const float*)d_in[14];
    const float* rWih = (const float*)d_in[15];
    const float* rWhh = (const float*)d_in[16];
    const float* rbih = (const float*)d_in[17];
    const float* rbhh = (const float*)d_in[18];
    const float* attW = (const float*)d_in[19];

    char* ws = (char*)d_ws;
    _Float16* he0  = (_Float16*)(ws + OFF_HE0);
    _Float16* he1  = (_Float16*)(ws + OFF_HE1);
    _Float16* he2  = (_Float16*)(ws + OFF_HE2);
    _Float16* hwih = (_Float16*)(ws + OFF_WIH);
    _Float16* hwhh = (_Float16*)(ws + OFF_WHH);
    float*    agg0 = (float*)(ws + OFF_AGG0);
    float*    agg1 = (float*)(ws + OFF_AGG1);
    float*    tbl1 = (float*)(ws + OFF_TBL1);

    float* out  = (float*)d_out;
    float* outc = out;
    float* outp = out + (size_t)NB * DIM;
    float* outn = out + (size_t)2 * NB * DIM;

    // 1) fp16 conversion of embeddings + weights
    {
        int total4 = (CN0 + CN1 + CN2) * DIM / 4 + 2 * (2 * 3 * DIM * DIM / 4);
        int blocks = (total4 + 255) / 256;
        prep_kernel<<<blocks, 256, 0, stream>>>(emb0, emb1, emb2, rWih, rWhh,
                                                he0, he1, he2, hwih, hwhh);
    }
    // 2) RNN-mean aggregations: c batch (4096 nodes) + full type-1 table (2048)
    {
        dim3 grid(NB / GMT + T1PAD / GMT, 6);
        rnn_kernel<<<grid, 64, 0, stream>>>(c_ids, nb00, nb01, nb02, nb10, nb11, nb12,
                                            he0, he1, he2, hwih, hwhh, rbih, rbhh,
                                            agg0, agg1);
    }
    // 3) attention combine
    {
        int blocks = NB / 4 + T1PAD / 4;
        att_kernel<<<blocks, 256, 0, stream>>>(c_ids, emb0, emb1, attW, agg0, agg1,
                                               outc, tbl1);
    }
    // 4) gather pos/neg outputs
    {
        int blocks = 2 * NB * 32 / 256;
        gather_kernel<<<blocks, 256, 0, stream>>>(pos_ids, neg_ids, tbl1, outp, outn);
    }
}